// Round 3
// baseline (577.689 us; speedup 1.0000x reference)
//
#include <hip/hip_runtime.h>

// Linear-chain CRF log-partition (backward DP), B=64, S=1024, T=128.
//
// r14 = r12/r13 single-wave matvec + the CORRECT register-residency fix.
//
// r13 post-mortem: KEEP16 (input-only "v" asm) does NOT pin live ranges —
// LLVM rematerializes E (reload transitions + v_exp + pack) to satisfy the
// asm each iteration, same as it does to feed the dot loop. VGPR_Count
// stayed 132 and dur was byte-identical. Counter arithmetic: active-SIMD
// VALUBusy 59% x 1183 cyc/step = ~700 issue-cyc vs ~350 expected = ~175
// extra instrs/step ~= remat of 128 E values. (Retro-check: r11 also shows
// a ~60-instr excess = remat of its 32 E regs. The tax was always there.)
//
// Fix: make E values NON-REMATERIALIZABLE. After computing each packed
// pair, pass it through a one-shot copy-through asm:
//     asm volatile("" : "+v"(EuA[k]));
// The SSA definition becomes an opaque asm output -> LLVM cannot recompute
// it; with ~180 regs needed against a 256-reg budget (waves_per_eu(1,1)),
// the allocator must hold them resident. In-loop KEEP16s dropped (useless).
//
// Verification gate: VGPR_Count must jump to ~190-210. If it stays 132,
// the residency theory is falsified -> pivot to multi-batch MFMA design.
//
// Structure (unchanged from r12/r13, both passed absmax 0.0):
//   - ONE wave per block; lane l owns rows 2l, 2l+1, all 128 cols.
//   - no s_barrier (single wave; lgkmcnt ordering only)
//   - gather = 16 uniform-address ds_read_b128 (broadcast, conflict-free)
//   - no cross-lane reduction; z via readfirstlane
// Numerics: publish v' = q*u*e^{-GHAT} (f16); q <- (E v')*rcp(z);
// Lam += GHAT + log z.

typedef _Float16 h2 __attribute__((ext_vector_type(2)));

#define B_  64
#define S_  1024
#define T_  128
#define PAD_IDX 0
#define EOS_IDX 3
#define BOT_IDX 1
#define GHAT         5.35f
#define EXP_NEG_GHAT 0.004736892f   // e^{-5.35}

#if defined(__has_builtin)
#if __has_builtin(__builtin_amdgcn_fdot2)
#define HAS_FDOT2 1
#endif
#endif

static __device__ __forceinline__ float dot2acc(unsigned eu, unsigned pu, float c) {
  h2 a = __builtin_bit_cast(h2, eu);
  h2 b = __builtin_bit_cast(h2, pu);
#ifdef HAS_FDOT2
  return __builtin_amdgcn_fdot2(a, b, c, false);
#else
  return fmaf((float)a.x, (float)b.x, fmaf((float)a.y, (float)b.y, c));
#endif
}

__global__ __launch_bounds__(64)
__attribute__((amdgpu_waves_per_eu(1, 1)))
void crf_logz_kernel(
    const int*   __restrict__ W,
    const float* __restrict__ emissions,
    const float* __restrict__ transitions,
    float*       __restrict__ out)
{
  const int b  = blockIdx.x;
  const int l  = threadIdx.x;        // 0..63 — exactly one wave
  const int rA = 2 * l;              // this lane owns rows rA, rA+1

  __shared__ __align__(16) unsigned vbuf[T_ / 2];   // 64 packed f16 pairs (256 B)

  // ---- E rows rA, rA+1, ALL 128 cols as packed f16 pairs (128 VGPRs)
  unsigned EuA[64], EuB[64];
  {
    const float2* ta = (const float2*)(transitions + (size_t)rA * T_);
    const float2* tb = (const float2*)(transitions + (size_t)(rA + 1) * T_);
    #pragma unroll
    for (int k = 0; k < 64; ++k) {
      float2 x = ta[k], y = tb[k];
      h2 ex, ey;
      ex.x = (_Float16)__expf(x.x); ex.y = (_Float16)__expf(x.y);
      ey.x = (_Float16)__expf(y.x); ey.y = (_Float16)__expf(y.y);
      EuA[k] = __builtin_bit_cast(unsigned, ex);
      EuB[k] = __builtin_bit_cast(unsigned, ey);
      // OPAQUE PIN: definition becomes an asm output -> cannot be
      // rematerialized; forces true VGPR residency for the kernel's life.
      asm volatile("" : "+v"(EuA[k]));
      asm volatile("" : "+v"(EuB[k]));
    }
  }

  const int*    Wrow = W + b * S_;
  const float2* emb2 = (const float2*)(emissions + (size_t)b * S_ * T_) + l;

  float2 q;  q.x = 1.0f; q.y = 1.0f;   // exp-state rows rA, rA+1
  float  Lam = 0.0f;
  float  z   = 1.0f;                   // previous row-0 value (uniform)

  // 4-deep em prefetch: slot0 holds consumed index i
  float2 e0 = emb2[(size_t)(S_ - 1) * 64];
  float2 e1 = emb2[(size_t)(S_ - 2) * 64];
  float2 e2 = emb2[(size_t)(S_ - 3) * 64];
  float2 e3 = emb2[(size_t)(S_ - 4) * 64];
  float2 us0, us1;
  us0.x = __expf(e0.x) * EXP_NEG_GHAT; us0.y = __expf(e0.y) * EXP_NEG_GHAT;
  us1.x = __expf(e1.x) * EXP_NEG_GHAT; us1.y = __expf(e1.y) * EXP_NEG_GHAT;

  for (int c = 15; c >= 0; --c) {
    // one vector load of 64 token ids -> uniform 64-bit activity mask (SGPRs)
    int wtok = Wrow[(c << 6) + l];
    unsigned long long m = __ballot((wtok != PAD_IDX) & (wtok != EOS_IDX));
    const int lo = (c == 0) ? 1 : 0;          // i==0 is never consumed

    for (int bit = 63; bit >= lo; --bit) {
      const int i = (c << 6) + bit;           // consumed emission index
      int pf = i - 4; pf &= ~(pf >> 31);      // max(i-4, 0): tail re-read is harmless
      float2 en = emb2[(size_t)pf * 64];      // prefetch (vmcnt, not drained)

      const bool active = (long long)m < 0;   // top bit; wave-uniform
      m <<= 1;

      if (active) {
        // publish v' = q .* us  (each lane writes its own packed pair)
        h2 vh; vh.x = (_Float16)(q.x * us0.x); vh.y = (_Float16)(q.y * us0.y);
        vbuf[l] = __builtin_bit_cast(unsigned, vh);

        float rz = __builtin_amdgcn_rcpf(z);  // uniform; off the dot chain
        Lam += GHAT + __logf(z);              // exact compensation (off-path)

        // gather ALL of v' (uniform-address broadcast reads, conflict-free);
        // lgkmcnt ordering by the compiler — no barrier (single wave)
        const uint4* vb = (const uint4*)vbuf;
        float aA0=0.f,aA1=0.f,aA2=0.f,aA3=0.f;
        float aB0=0.f,aB1=0.f,aB2=0.f,aB3=0.f;
        #pragma unroll
        for (int k = 0; k < 16; ++k) {
          uint4 pv = vb[k];                   // pairs 4k..4k+3 = cols 8k..8k+7
          aA0 = dot2acc(EuA[4*k+0], pv.x, aA0);
          aA1 = dot2acc(EuA[4*k+1], pv.y, aA1);
          aA2 = dot2acc(EuA[4*k+2], pv.z, aA2);
          aA3 = dot2acc(EuA[4*k+3], pv.w, aA3);
          aB0 = dot2acc(EuB[4*k+0], pv.x, aB0);
          aB1 = dot2acc(EuB[4*k+1], pv.y, aB1);
          aB2 = dot2acc(EuB[4*k+2], pv.z, aB2);
          aB3 = dot2acc(EuB[4*k+3], pv.w, aB3);
        }
        float sA = (aA0 + aA1) + (aA2 + aA3); // complete row sums — no DPP
        float sB = (aB0 + aB1) + (aB2 + aB3);

        q.x = sA * rz;
        q.y = sB * rz;
        // next-step normalizer = new row-0 value (lane 0's q.x)
        z = __builtin_bit_cast(float,
              __builtin_amdgcn_readfirstlane(__builtin_bit_cast(int, q.x)));
      }
      // shift prefetch pipeline
      e0 = e1; us0 = us1;
      e1 = e2;
      e2 = e3;
      e3 = en;
      us1.x = __expf(e1.x) * EXP_NEG_GHAT;
      us1.y = __expf(e1.y) * EXP_NEG_GHAT;
    }
  }

  // ---- epilogue: f_r = trans[BOT,r] + em[b,0,r] + log q_r; logZ = Lam + LSE(f)
  float2 tb2 = *(const float2*)(transitions + (size_t)BOT_IDX * T_ + rA);
  float fx = tb2.x + e0.x + __logf(q.x);      // e0 ended as em[b,0,rA..rA+1]
  float fy = tb2.y + e0.y + __logf(q.y);
  float mx = fmaxf(fx, fy);
  #pragma unroll
  for (int off = 32; off; off >>= 1) mx = fmaxf(mx, __shfl_xor(mx, off));
  float s = __expf(fx - mx) + __expf(fy - mx);
  #pragma unroll
  for (int off = 32; off; off >>= 1) s += __shfl_xor(s, off);
  if (l == 0) out[b] = Lam + mx + __logf(s);
}

extern "C" void kernel_launch(void* const* d_in, const int* in_sizes, int n_in,
                              void* d_out, int out_size, void* d_ws, size_t ws_size,
                              hipStream_t stream) {
  const int*   W     = (const int*)d_in[0];
  const float* em    = (const float*)d_in[1];
  const float* trans = (const float*)d_in[2];
  float*       out   = (float*)d_out;
  (void)in_sizes; (void)n_in; (void)out_size; (void)d_ws; (void)ws_size;
  crf_logz_kernel<<<B_, 64, 0, stream>>>(W, em, trans, out);
}

// Round 4
// 546.953 us; speedup vs baseline: 1.0562x; 1.0562x over previous
//
#include <hip/hip_runtime.h>

// Linear-chain CRF log-partition (backward DP), B=64, S=1024, T=128.
//
// r15 = 2-wave, one-full-row-per-lane design, sized to FIT the observed
// ~128-132 VGPR allocator cap.
//
// r12-r14 post-mortem: VGPR_Count pinned at 132 across 64/256-thread
// variants; "+v" anti-remat pins gave slightly lower VALUBusy + slightly
// higher time (spill signature). Conclusion: the register budget is
// hard-capped ~128-132 (waves_per_eu attr not honored); any design with
// >132 resident regs pays per-step spill/remat on the serial chain.
//
// r15 design: 128 threads (2 waves), lane tid owns row j=tid of E:
//   - E row = 64 packed f16-pair VGPRs; + 8 accs + misc ~= 116 regs < cap.
//   - lane computes the FULL 128-col dot -> no DPP reduction at all.
//   - barrier is 2-wave (vs r11's 4-wave), one per active step, via
//     raw "s_waitcnt lgkmcnt(0); s_barrier" (no vmcnt drain -> em
//     prefetch stays in flight across steps, r11-proven).
//   - v' exchange: each lane ds_write_b16 its f16 v'; all lanes gather
//     via 16 broadcast ds_read_b128 (conflict-free), overlapping dots.
//   - z via parity zslot LDS (r11-proven double-buffer, no race).
//   - __launch_bounds__(128, 1): official HIP min-waves knob; design no
//     longer depends on it, but it may lift the cap for free headroom.
//
// Numerics (r11/r12-proven, absmax 0.0): publish v' = q*us*e^{-GHAT}
// (f16); q <- (E v')*rcp(z), z = prev row-0 q; Lam += GHAT + log z.

typedef _Float16 h2 __attribute__((ext_vector_type(2)));

#define B_  64
#define S_  1024
#define T_  128
#define PAD_IDX 0
#define EOS_IDX 3
#define BOT_IDX 1
#define GHAT         5.35f
#define EXP_NEG_GHAT 0.004736892f   // e^{-5.35}

#if defined(__has_builtin)
#if __has_builtin(__builtin_amdgcn_fdot2)
#define HAS_FDOT2 1
#endif
#endif

static __device__ __forceinline__ float dot2acc(unsigned eu, unsigned pu, float c) {
  h2 a = __builtin_bit_cast(h2, eu);
  h2 b = __builtin_bit_cast(h2, pu);
#ifdef HAS_FDOT2
  return __builtin_amdgcn_fdot2(a, b, c, false);
#else
  return fmaf((float)a.x, (float)b.x, fmaf((float)a.y, (float)b.y, c));
#endif
}

__global__ __launch_bounds__(128, 1)
__attribute__((amdgpu_waves_per_eu(1, 1)))
void crf_logz_kernel(
    const int*   __restrict__ W,
    const float* __restrict__ emissions,
    const float* __restrict__ transitions,
    float*       __restrict__ out)
{
  const int b   = blockIdx.x;
  const int tid = threadIdx.x;       // 0..127 — two waves
  const int l   = tid & 63;
  const int j   = tid;               // owned row of E / beta

  __shared__ __align__(16) unsigned short vbuf[2][T_];  // [parity][row] f16 v'
  __shared__ float zslot[2];
  __shared__ float fbuf[T_];

  // ---- E row j (all 128 cols) as 64 packed f16 pairs -> 64 VGPRs
  unsigned Eu[64];
  {
    const float2* tr = (const float2*)(transitions + (size_t)j * T_);
    #pragma unroll
    for (int k = 0; k < 64; ++k) {
      float2 x = tr[k];
      h2 e; e.x = (_Float16)__expf(x.x); e.y = (_Float16)__expf(x.y);
      Eu[k] = __builtin_bit_cast(unsigned, e);
    }
  }

  const int*   Wrow = W + b * S_;
  const float* emp  = emissions + (size_t)b * S_ * T_ + j;

  float q   = 1.0f;                  // exp-state for row j
  float Lam = 0.0f;
  int   par = 0;

  // 4-deep em prefetch (scalar per lane; lanes coalesce across the row)
  float e0 = emp[(size_t)(S_ - 1) * T_];
  float e1 = emp[(size_t)(S_ - 2) * T_];
  float e2 = emp[(size_t)(S_ - 3) * T_];
  float e3 = emp[(size_t)(S_ - 4) * T_];
  float us0 = __expf(e0) * EXP_NEG_GHAT;
  float us1 = __expf(e1) * EXP_NEG_GHAT;

  for (int c = 15; c >= 0; --c) {
    // 64 token ids -> uniform 64-bit activity mask (identical in both waves)
    int wtok = Wrow[(c << 6) + l];
    unsigned long long m = __ballot((wtok != PAD_IDX) & (wtok != EOS_IDX));
    const int lo = (c == 0) ? 1 : 0;          // i==0 is never consumed

    for (int bit = 63; bit >= lo; --bit) {
      const int i = (c << 6) + bit;           // consumed emission index
      int pf = i - 4; pf &= ~(pf >> 31);      // max(i-4,0): tail re-read harmless
      float en = emp[(size_t)pf * T_];        // prefetch (vmcnt, not drained)

      const bool active = (long long)m < 0;   // top bit; uniform across block
      m <<= 1;

      if (active) {
        // publish v' = q * us  (one f16 per lane = its row)
        _Float16 vh = (_Float16)(q * us0);
        vbuf[par][j] = __builtin_bit_cast(unsigned short, vh);
        if (tid == 0) zslot[par] = q;         // z for THIS step = prev row-0 q

        // drain own LDS writes, then barrier; NO vmcnt drain (prefetch lives)
        asm volatile("s_waitcnt lgkmcnt(0)\n\ts_barrier" ::: "memory");

        float z = zslot[par];
        const uint4* vb = (const uint4*)&vbuf[par][0];
        float a0=0.f,a1=0.f,a2=0.f,a3=0.f,a4=0.f,a5=0.f,a6=0.f,a7=0.f;
        #pragma unroll
        for (int k = 0; k < 16; ++k) {
          uint4 pv = vb[k];                   // broadcast: pairs 4k..4k+3
          if (k & 1) {
            a4 = dot2acc(Eu[4*k+0], pv.x, a4);
            a5 = dot2acc(Eu[4*k+1], pv.y, a5);
            a6 = dot2acc(Eu[4*k+2], pv.z, a6);
            a7 = dot2acc(Eu[4*k+3], pv.w, a7);
          } else {
            a0 = dot2acc(Eu[4*k+0], pv.x, a0);
            a1 = dot2acc(Eu[4*k+1], pv.y, a1);
            a2 = dot2acc(Eu[4*k+2], pv.z, a2);
            a3 = dot2acc(Eu[4*k+3], pv.w, a3);
          }
        }
        float s = ((a0 + a4) + (a1 + a5)) + ((a2 + a6) + (a3 + a7));

        float rz = __builtin_amdgcn_rcpf(z);  // uniform; off the dot chain
        q = s * rz;
        Lam += GHAT + __logf(z);              // exact compensation (off-path)
        par ^= 1;
      }
      // shift prefetch pipeline
      e0 = e1; us0 = us1;
      e1 = e2;
      e2 = e3;
      e3 = en;
      us1 = __expf(e1) * EXP_NEG_GHAT;
    }
  }

  // ---- epilogue: f_j = trans[BOT,j] + em[b,0,j] + log q_j; out = Lam+LSE(f)
  float f = transitions[(size_t)BOT_IDX * T_ + j] + e0 + __logf(q);
  fbuf[j] = f;
  __syncthreads();
  if (tid < 64) {
    float x0 = fbuf[tid], x1 = fbuf[tid + 64];
    float mx = fmaxf(x0, x1);
    #pragma unroll
    for (int off = 32; off; off >>= 1) mx = fmaxf(mx, __shfl_xor(mx, off));
    float s = __expf(x0 - mx) + __expf(x1 - mx);
    #pragma unroll
    for (int off = 32; off; off >>= 1) s += __shfl_xor(s, off);
    if (tid == 0) out[b] = Lam + mx + __logf(s);
  }
}

extern "C" void kernel_launch(void* const* d_in, const int* in_sizes, int n_in,
                              void* d_out, int out_size, void* d_ws, size_t ws_size,
                              hipStream_t stream) {
  const int*   W     = (const int*)d_in[0];
  const float* em    = (const float*)d_in[1];
  const float* trans = (const float*)d_in[2];
  float*       out   = (float*)d_out;
  (void)in_sizes; (void)n_in; (void)out_size; (void)d_ws; (void)ws_size;
  crf_logz_kernel<<<B_, 128, 0, stream>>>(W, em, trans, out);
}

// Round 5
// 434.331 us; speedup vs baseline: 1.3301x; 1.2593x over previous
//
#include <hip/hip_runtime.h>

// Linear-chain CRF log-partition (backward DP), B=64, S=1024, T=128.
//
// r16 = r11 structure (431us, proven) + ZERO-GLOBAL inner loop.
//
// r11-r15 unified post-mortem: every variant spent ~1000-1150 cyc/step;
// the common cause is in-loop GLOBAL traffic on the serial chain (E remat
// from invariant loads and/or the em prefetch), whose ~200-cyc L2 latency
// cannot be hidden at 1-chain-per-CU occupancy. r15's VGPR=52 proved the
// allocator will always prefer remat/reload of big arrays; r14's "+v" pin
// proved it prefers scratch spill over high allocation. So: keep E small
// (32 regs, r11 quad layout) and make the inner loop LDS-only:
//
//  1) Emissions are chunk-staged into LDS (64 steps x 128 f32 = 32 KB,
//     double-buffered) via __builtin_amdgcn_global_load_lds width=16.
//     8 async issues at chunk start; ONE vmcnt(0)+barrier per 64 steps.
//     In-loop em read = 1 broadcast ds_read_b64/lane, 1-step pipelined.
//     In-loop waits are lgkmcnt-only (staging stays in flight, r11-style).
//  2) W prefetched one chunk ahead into a register; ballot at the
//     boundary after the shared vmcnt drain.
//  3) Register need ~80 < 132 -> no remat pressure on E.
//
// Numerics IDENTICAL to r11 (passed, absmax 0.0): publish v' = q*us*
// e^{-GHAT} (f16, dead-beat, no feedback); barrier; z = zslot[par];
// q <- (E v')*rcp(z); Lam += GHAT + log z; us = exp(em f32)*e^{-GHAT}.

typedef _Float16 h2 __attribute__((ext_vector_type(2)));

#define B_  64
#define S_  1024
#define T_  128
#define PAD_IDX 0
#define EOS_IDX 3
#define BOT_IDX 1
#define GHAT         5.35f
#define EXP_NEG_GHAT 0.004736892f   // e^{-5.35}

#define CHUNK_BYTES  32768          // 64 steps * 128 rows * 4 B

#if defined(__has_builtin)
#if __has_builtin(__builtin_amdgcn_fdot2)
#define HAS_FDOT2 1
#endif
#endif

static __device__ __forceinline__ float dot2acc(unsigned eu, unsigned pu, float c) {
  h2 a = __builtin_bit_cast(h2, eu);
  h2 b = __builtin_bit_cast(h2, pu);
#ifdef HAS_FDOT2
  return __builtin_amdgcn_fdot2(a, b, c, false);
#else
  return fmaf((float)a.x, (float)b.x, fmaf((float)a.y, (float)b.y, c));
#endif
}

// x + (x from quad-permuted lane) via DPP; ctrl is an immediate (template)
template <int CTRL>
static __device__ __forceinline__ float dpp_add(float x) {
  int p = __builtin_amdgcn_update_dpp(0, __builtin_bit_cast(int, x),
                                      CTRL, 0xF, 0xF, true);
  return x + __builtin_bit_cast(float, p);
}

typedef __attribute__((address_space(3))) void  lds_void_t;
typedef __attribute__((address_space(1))) const void gmem_void_t;

__global__ __launch_bounds__(256)
void crf_logz_kernel(
    const int*   __restrict__ W,
    const float* __restrict__ emissions,
    const float* __restrict__ transitions,
    float*       __restrict__ out)
{
  const int b   = blockIdx.x;
  const int tid = threadIdx.x;
  const int l   = tid & 63;
  const int Q   = tid >> 2;          // quad id 0..63 -> rows 2Q, 2Q+1
  const int cp  = tid & 3;           // column quarter: cols [32cp, 32cp+32)
  const int rA  = 2 * Q;

  __shared__ __align__(16) float    embuf[2][64 * T_];  // 2 x 32 KB em chunks
  __shared__ __align__(16) unsigned vbuf[2][T_ / 2];    // packed half2 per quad
  __shared__ float zslot[2];
  __shared__ float fbuf[T_];

  // ---- E rows rA,rA+1, cols [32cp,+32) as 32 packed f16 pairs (32 VGPRs)
  unsigned Eu[32];   // [0..15] row A pairs, [16..31] row B pairs
  {
    const float2* ta = (const float2*)(transitions + (size_t)rA * T_ + 32 * cp);
    const float2* tb = (const float2*)(transitions + (size_t)(rA + 1) * T_ + 32 * cp);
    #pragma unroll
    for (int k = 0; k < 16; ++k) {
      float2 x = ta[k], y = tb[k];
      h2 ex, ey;
      ex.x = (_Float16)__expf(x.x); ex.y = (_Float16)__expf(x.y);
      ey.x = (_Float16)__expf(y.x); ey.y = (_Float16)__expf(y.y);
      Eu[k]      = __builtin_bit_cast(unsigned, ex);
      Eu[16 + k] = __builtin_bit_cast(unsigned, ey);
    }
  }

  if (tid == 0) { zslot[0] = 1.0f; zslot[1] = 1.0f; }

  const int*  Wrow = W + b * S_;
  const char* emB  = (const char*)(emissions + (size_t)b * S_ * T_);

  // async stage of one 32 KB chunk into embuf[nb]; 8 rounds x 4 KB.
  // tid*16 = wave*1024 + lane*16, so the per-wave LDS base is
  // embuf[nb] + r*4096 + (tid>>6)*1024 and HW adds lane*16.
  auto stage_chunk = [&](int chunk, int nb) {
    const char* gbase = emB + (size_t)chunk * CHUNK_BYTES + (size_t)tid * 16;
    char* lbase = (char*)&embuf[nb][0] + ((tid >> 6) << 10);
    #pragma unroll
    for (int r = 0; r < 8; ++r) {
      __builtin_amdgcn_global_load_lds(
          (gmem_void_t*)(gbase + (r << 12)),
          (lds_void_t*)(lbase + (r << 12)),
          16, 0, 0);
    }
  };

  // prologue: stage chunk 15 -> buf 0; prefetch chunk 15's W ids
  stage_chunk(15, 0);
  int wtok = Wrow[(15 << 6) + l];
  __syncthreads();                    // full drain (vmcnt+lgkm) once
  unsigned long long m = __ballot((wtok != PAD_IDX) & (wtok != EOS_IDX));

  float2 q;  q.x = 1.0f; q.y = 1.0f;  // exp-state rows rA, rA+1
  float  Lam = 0.0f;
  int    par = 0;
  int    cur = 0;

  for (int c = 15; c >= 0; --c) {
    if (c > 0) {
      stage_chunk(c - 1, cur ^ 1);          // async; drains at boundary only
      wtok = Wrow[((c - 1) << 6) + l];      // W one chunk ahead (vmcnt)
    }
    // init 1-deep em pipeline for this chunk: us for within-chunk step 63
    float2 ec = *(const float2*)&embuf[cur][(63 << 7) + rA];
    float2 us;
    us.x = __expf(ec.x) * EXP_NEG_GHAT;
    us.y = __expf(ec.y) * EXP_NEG_GHAT;

    const int lo = (c == 0) ? 1 : 0;        // i==0 is never consumed

    for (int bit = 63; bit >= lo; --bit) {
      const bool active = (long long)m < 0; // top bit; uniform across block
      m <<= 1;

      if (active) {                         // block-uniform branch
        // publish v' = q .* us  (one lane per quad writes the packed pair)
        h2 vh; vh.x = (_Float16)(q.x * us.x); vh.y = (_Float16)(q.y * us.y);
        if (cp == 0) vbuf[par][Q] = __builtin_bit_cast(unsigned, vh);
        // drain own DS write, then barrier; NO vmcnt drain (staging lives)
        asm volatile("s_waitcnt lgkmcnt(0)\n\ts_barrier" ::: "memory");

        float z = zslot[par];
        const uint4* vb = ((const uint4*)&vbuf[par][0]) + (cp << 2);
        float aA0=0.f,aA1=0.f,aA2=0.f,aA3=0.f;
        float aB0=0.f,aB1=0.f,aB2=0.f,aB3=0.f;
        #pragma unroll
        for (int k = 0; k < 4; ++k) {
          uint4 pv = vb[k];                 // 4x ds_read_b128 per lane
          aA0 = dot2acc(Eu[4*k+0],      pv.x, aA0);
          aA1 = dot2acc(Eu[4*k+1],      pv.y, aA1);
          aA2 = dot2acc(Eu[4*k+2],      pv.z, aA2);
          aA3 = dot2acc(Eu[4*k+3],      pv.w, aA3);
          aB0 = dot2acc(Eu[16+4*k+0],   pv.x, aB0);
          aB1 = dot2acc(Eu[16+4*k+1],   pv.y, aB1);
          aB2 = dot2acc(Eu[16+4*k+2],   pv.z, aB2);
          aB3 = dot2acc(Eu[16+4*k+3],   pv.w, aB3);
        }
        float sA = (aA0 + aA1) + (aA2 + aA3);
        float sB = (aB0 + aB1) + (aB2 + aB3);
        // complete row sums across the quad: xor1 then xor2
        sA = dpp_add<0xB1>(sA); sA = dpp_add<0x4E>(sA);
        sB = dpp_add<0xB1>(sB); sB = dpp_add<0x4E>(sB);

        float rz = __builtin_amdgcn_rcpf(z);  // uniform
        q.x = sA * rz;
        q.y = sB * rz;
        if (tid == 0) zslot[par ^ 1] = q.x;   // row 0's value for NEXT step
        Lam += GHAT + __logf(z);              // exact compensation (off-path)
        par ^= 1;
      }

      // advance em pipeline from LDS (same buffer; clamp harmless at tail)
      int nb2 = bit - 1; nb2 &= ~(nb2 >> 31);       // max(bit-1, 0)
      float2 en = *(const float2*)&embuf[cur][(nb2 << 7) + rA];
      us.x = __expf(en.x) * EXP_NEG_GHAT;
      us.y = __expf(en.y) * EXP_NEG_GHAT;
    }

    if (c > 0) {
      // chunk boundary: all staging loads (and next W) land; flip buffers
      asm volatile("s_waitcnt vmcnt(0)\n\ts_barrier" ::: "memory");
      m = __ballot((wtok != PAD_IDX) & (wtok != EOS_IDX));
      cur ^= 1;
    }
  }

  // ---- epilogue: f_r = trans[BOT,r] + em[b,0,r] + log q_r + Lam
  // chunk 0 still lives in embuf[cur]; step 0 = em[b,0,*]
  if (cp == 0) {
    float2 tb2 = *(const float2*)(transitions + (size_t)BOT_IDX * T_ + rA);
    float2 e00 = *(const float2*)&embuf[cur][rA];
    float2 f;
    f.x = tb2.x + e00.x + __logf(q.x);
    f.y = tb2.y + e00.y + __logf(q.y);
    *(float2*)&fbuf[rA] = f;
  }
  __syncthreads();
  if (tid < 64) {
    float x0 = fbuf[tid], x1 = fbuf[tid + 64];
    float m2 = fmaxf(x0, x1);
    #pragma unroll
    for (int off = 32; off; off >>= 1) m2 = fmaxf(m2, __shfl_xor(m2, off));
    float s = __expf(x0 - m2) + __expf(x1 - m2);
    #pragma unroll
    for (int off = 32; off; off >>= 1) s += __shfl_xor(s, off);
    if (tid == 0) out[b] = Lam + m2 + __logf(s);
  }
}

extern "C" void kernel_launch(void* const* d_in, const int* in_sizes, int n_in,
                              void* d_out, int out_size, void* d_ws, size_t ws_size,
                              hipStream_t stream) {
  const int*   W     = (const int*)d_in[0];
  const float* em    = (const float*)d_in[1];
  const float* trans = (const float*)d_in[2];
  float*       out   = (float*)d_out;
  (void)in_sizes; (void)n_in; (void)out_size; (void)d_ws; (void)ws_size;
  crf_logz_kernel<<<B_, 256, 0, stream>>>(W, em, trans, out);
}